// Round 3
// baseline (1209.276 us; speedup 1.0000x reference)
//
#include <hip/hip_runtime.h>

#define BATCH   1024
#define MSIZE   65536
#define KDIM    256
#define CHOOSEK 128
#define SELK    160      // screening margin: per-quarter top-SELK superset absorbs bf16+u16 error
#define BETA    1e-8f
#define ALPHA   0.5f

typedef short bf16x8 __attribute__((ext_vector_type(8)));
typedef float f32x4  __attribute__((ext_vector_type(4)));

#define LDA 40    // bf16 LDS row: 32 + 8 pad
#define LDC 136   // u16 epilogue tile row: 128 + 8 pad (272 B, 16B-aligned)

__device__ inline unsigned int pack2bf(float a, float b) {   // RNE fp32->bf16 pair
    unsigned int ua = __float_as_uint(a);
    unsigned int ub = __float_as_uint(b);
    ua += 0x7fffu + ((ua >> 16) & 1u);
    ub += 0x7fffu + ((ub >> 16) & 1u);
    return (ua >> 16) | (ub & 0xffff0000u);
}

// -------------------------------------------------------------------------
// K1: bf16-MFMA screening GEMM. 128x128 tile / 256 threads, 4 waves, 4x4
// 16x16x32 MFMAs each, BK=32. Epilogue: monotone log-domain u16 sort key
// z = sim + log(hist+beta)  (z<0 always)  ->  key16 = (~bits(z))>>16,
// staged in LDS, written out coalesced (256 B per thread-pair).
// -------------------------------------------------------------------------
__global__ __launch_bounds__(256)
void score_u16_kernel(const float* __restrict__ q,
                      const float* __restrict__ key,
                      const float* __restrict__ hist,
                      unsigned short* __restrict__ s16)
{
    __shared__ unsigned short As[128 * LDA];
    __shared__ unsigned short Bs[128 * LDA];
    __shared__ unsigned short Cs[128 * LDC];
    const int tid  = threadIdx.x;
    const int b0   = blockIdx.x * 128;
    const int n0   = blockIdx.y * 128;
    const int lane = tid & 63;
    const int wave = tid >> 6;
    const int wm   = (wave >> 1) * 64;
    const int wn   = (wave & 1) * 64;
    const int l15  = lane & 15;
    const int l4   = lane >> 4;

    const int srow = tid >> 1;
    const int sseg = (tid & 1) * 16;

    f32x4 acc[4][4] = {};

    const float* gA = q   + (size_t)(b0 + srow) * KDIM + sseg;
    const float* gB = key + (size_t)(n0 + srow) * KDIM + sseg;
    uint4* wA = (uint4*)((char*)As + srow * (LDA * 2) + sseg * 2);
    uint4* wB = (uint4*)((char*)Bs + srow * (LDA * 2) + sseg * 2);

    for (int ks = 0; ks < KDIM; ks += 32) {
        float4 a0 = *(const float4*)(gA + ks);
        float4 a1 = *(const float4*)(gA + ks + 4);
        float4 a2 = *(const float4*)(gA + ks + 8);
        float4 a3 = *(const float4*)(gA + ks + 12);
        float4 c0 = *(const float4*)(gB + ks);
        float4 c1 = *(const float4*)(gB + ks + 4);
        float4 c2 = *(const float4*)(gB + ks + 8);
        float4 c3 = *(const float4*)(gB + ks + 12);

        uint4 pa0 = make_uint4(pack2bf(a0.x, a0.y), pack2bf(a0.z, a0.w),
                               pack2bf(a1.x, a1.y), pack2bf(a1.z, a1.w));
        uint4 pa1 = make_uint4(pack2bf(a2.x, a2.y), pack2bf(a2.z, a2.w),
                               pack2bf(a3.x, a3.y), pack2bf(a3.z, a3.w));
        uint4 pb0 = make_uint4(pack2bf(c0.x, c0.y), pack2bf(c0.z, c0.w),
                               pack2bf(c1.x, c1.y), pack2bf(c1.z, c1.w));
        uint4 pb1 = make_uint4(pack2bf(c2.x, c2.y), pack2bf(c2.z, c2.w),
                               pack2bf(c3.x, c3.y), pack2bf(c3.z, c3.w));
        wA[0] = pa0; wA[1] = pa1;
        wB[0] = pb0; wB[1] = pb1;
        __syncthreads();

        bf16x8 af[4], bfr[4];
#pragma unroll
        for (int i = 0; i < 4; ++i)
            af[i] = *(const bf16x8*)((const char*)As + (wm + i * 16 + l15) * (LDA * 2) + l4 * 16);
#pragma unroll
        for (int j = 0; j < 4; ++j)
            bfr[j] = *(const bf16x8*)((const char*)Bs + (wn + j * 16 + l15) * (LDA * 2) + l4 * 16);
#pragma unroll
        for (int i = 0; i < 4; ++i)
#pragma unroll
            for (int j = 0; j < 4; ++j)
                acc[i][j] = __builtin_amdgcn_mfma_f32_16x16x32_bf16(af[i], bfr[j], acc[i][j], 0, 0, 0);
        __syncthreads();
    }

    // epilogue: C/D layout col = lane&15, row = (lane>>4)*4 + reg
    float lhj[4];
#pragma unroll
    for (int j = 0; j < 4; ++j)
        lhj[j] = __logf(hist[n0 + wn + j * 16 + l15] + BETA);
#pragma unroll
    for (int i = 0; i < 4; ++i) {
        int r = wm + i * 16 + l4 * 4;
#pragma unroll
        for (int j = 0; j < 4; ++j) {
            int c = wn + j * 16 + l15;
#pragma unroll
            for (int reg = 0; reg < 4; ++reg) {
                float z = acc[i][j][reg] + lhj[j];            // < 0 always
                Cs[(r + reg) * LDC + c] =
                    (unsigned short)((~__float_as_uint(z)) >> 16);
            }
        }
    }
    __syncthreads();
    {   // coalesced write-out: thread pair (2t,2t+1) covers one 256 B row
        int row = tid >> 1, half = tid & 1;
        const uint4* srcp = (const uint4*)&Cs[row * LDC + half * 64];
        uint4* dstp = (uint4*)(s16 + (size_t)(b0 + row) * MSIZE + n0 + half * 64);
#pragma unroll
        for (int k = 0; k < 8; ++k) dstp[k] = srcp[k];
    }
}

// -------------------------------------------------------------------------
// K2: per (row, quarter) — load 16384 u16 chunk into LDS once (histogram
// built from registers in flight), two-level radix select of local top-SELK,
// write candidate col-offsets into the front of the (already consumed) own
// chunk: chunk[0]=count, chunk[1..count]=offsets. No extra workspace, no races.
// -------------------------------------------------------------------------
__global__ __launch_bounds__(256)
void chunk_select_kernel(unsigned short* __restrict__ s16)
{
    const int b   = blockIdx.x >> 2;
    const int qd  = blockIdx.x & 3;
    const int tid = threadIdx.x;
    unsigned short* chunk = s16 + (size_t)b * MSIZE + qd * 16384;

    __shared__ unsigned short data[16384];       // 32 KB
    __shared__ unsigned int hcnt[16 * 257];      // 16 replicated histograms
    __shared__ int stot[256];
    __shared__ int scal[4];                      // 0:H 1:nAbove 2:T16 3:count

    for (int i = tid; i < 16 * 257; i += 256) hcnt[i] = 0u;
    __syncthreads();

    uint4 v[8];
    const uint4* src = (const uint4*)chunk;
#pragma unroll
    for (int i = 0; i < 8; ++i) v[i] = src[i * 256 + tid];   // all loads in flight
    const int rep = (tid & 15) * 257;
#pragma unroll
    for (int i = 0; i < 8; ++i) {
        ((uint4*)data)[i * 256 + tid] = v[i];
        unsigned int w[4] = {v[i].x, v[i].y, v[i].z, v[i].w};
#pragma unroll
        for (int k = 0; k < 4; ++k) {
            atomicAdd(&hcnt[rep + ((w[k] >> 8) & 0xffu)], 1u);
            atomicAdd(&hcnt[rep + (w[k] >> 24)], 1u);
        }
    }
    __syncthreads();
    { unsigned int t = 0;
#pragma unroll
      for (int k = 0; k < 16; ++k) t += hcnt[k * 257 + tid];
      stot[tid] = (int)t; }
    __syncthreads();
    for (int off = 1; off < 256; off <<= 1) {    // suffix sum over high byte
        int val = stot[tid] + ((tid + off < 256) ? stot[tid + off] : 0);
        __syncthreads(); stot[tid] = val; __syncthreads();
    }
    { int sH = stot[tid], sN = (tid < 255) ? stot[tid + 1] : 0;
      if (sH >= SELK && sN < SELK) { scal[0] = tid; scal[1] = sN; } }
    __syncthreads();
    const int H = scal[0], nAbove = scal[1];

    for (int i = tid; i < 16 * 257; i += 256) hcnt[i] = 0u;
    __syncthreads();
    for (int i = 0; i < 8; ++i) {                // low-byte hist among high==H (from LDS)
        uint4 w4 = ((const uint4*)data)[i * 256 + tid];
        unsigned int w[4] = {w4.x, w4.y, w4.z, w4.w};
#pragma unroll
        for (int k = 0; k < 4; ++k) {
            unsigned int u0 = w[k] & 0xffffu, u1 = w[k] >> 16;
            if ((int)(u0 >> 8) == H) atomicAdd(&hcnt[rep + (u0 & 0xffu)], 1u);
            if ((int)(u1 >> 8) == H) atomicAdd(&hcnt[rep + (u1 & 0xffu)], 1u);
        }
    }
    __syncthreads();
    { unsigned int t = 0;
#pragma unroll
      for (int k = 0; k < 16; ++k) t += hcnt[k * 257 + tid];
      stot[tid] = (int)t; }
    __syncthreads();
    for (int off = 1; off < 256; off <<= 1) {
        int val = stot[tid] + ((tid + off < 256) ? stot[tid + off] : 0);
        __syncthreads(); stot[tid] = val; __syncthreads();
    }
    { int sH2 = nAbove + stot[tid];
      int sN2 = nAbove + ((tid < 255) ? stot[tid + 1] : 0);
      if (sH2 >= SELK && sN2 < SELK) scal[2] = (H << 8) | tid;
      if (tid == 0) scal[3] = 0; }
    __syncthreads();
    const unsigned int T16 = (unsigned int)scal[2];

    for (int i = 0; i < 8; ++i) {                // collect u16 >= T16 (from LDS)
        uint4 w4 = ((const uint4*)data)[i * 256 + tid];
        int base = (i * 256 + tid) * 8;
        unsigned int w[4] = {w4.x, w4.y, w4.z, w4.w};
#pragma unroll
        for (int k = 0; k < 4; ++k) {
            unsigned int u0 = w[k] & 0xffffu, u1 = w[k] >> 16;
            if (u0 >= T16) { int p = atomicAdd(&scal[3], 1);
                             if (p < 767) chunk[1 + p] = (unsigned short)(base + 2 * k); }
            if (u1 >= T16) { int p = atomicAdd(&scal[3], 1);
                             if (p < 767) chunk[1 + p] = (unsigned short)(base + 2 * k + 1); }
        }
    }
    __syncthreads();
    if (tid == 0) chunk[0] = (unsigned short)min(scal[3], 767);
}

// -------------------------------------------------------------------------
// K3: per row — gather <=3068 candidates from the 4 chunk fronts, exact fp32
// rescore, count-based exact top-128 (ties -> lower index, matches lax.top_k),
// result = sum(j*v)/sum(j), j = exp(sim-1)*(alpha*hist+beta).
// -------------------------------------------------------------------------
__global__ __launch_bounds__(256)
void rescore_kernel(const float* __restrict__ q,
                    const float* __restrict__ key,
                    const float* __restrict__ hist,
                    const float* __restrict__ vals,
                    const unsigned short* __restrict__ s16,
                    float* __restrict__ out)
{
    const int b   = blockIdx.x;
    const int tid = threadIdx.x;

    __shared__ float qs[KDIM];
    __shared__ int   cidx[3072];
    __shared__ float csc[3072], cjj[3072], cjv[3072];
    __shared__ int   cbase[5];
    __shared__ float wred[8];

    qs[tid] = q[(size_t)b * KDIM + tid];
    const unsigned short* row = s16 + (size_t)b * MSIZE;
    if (tid == 0) {
        int acc = 0;
#pragma unroll
        for (int qd = 0; qd < 4; ++qd) { cbase[qd] = acc; acc += row[qd * 16384]; }
        cbase[4] = acc;
    }
    __syncthreads();
#pragma unroll
    for (int qd = 0; qd < 4; ++qd) {
        const unsigned short* ch = row + qd * 16384;
        int base = cbase[qd], cnt = cbase[qd + 1] - base;
        for (int i = tid; i < cnt; i += 256)
            cidx[base + i] = qd * 16384 + ch[1 + i];
    }
    __syncthreads();
    const int ncand = cbase[4];                  // >= 640, <= 3068

    const int wave = tid >> 6, lane = tid & 63;
    for (int i = wave; i < ncand; i += 4) {      // exact fp32 rescore
        const int idx = cidx[i];
        float4 kk = *reinterpret_cast<const float4*>(&key[(size_t)idx * KDIM + lane * 4]);
        float4 qq = *reinterpret_cast<const float4*>(&qs[lane * 4]);
        float p = kk.x * qq.x + kk.y * qq.y + kk.z * qq.z + kk.w * qq.w;
#pragma unroll
        for (int off = 32; off > 0; off >>= 1) p += __shfl_xor(p, off, 64);
        if (lane == 0) {
            float e = expf(p - 1.0f);
            float h = hist[idx];
            csc[i] = e * (h + BETA);
            float j = e * (ALPHA * h + BETA);
            cjj[i] = j;
            cjv[i] = j * vals[idx];
        }
    }
    __syncthreads();

    float pn = 0.f, pd = 0.f;                    // exact top-128 by rank count
    for (int i = tid; i < ncand; i += 256) {
        float si = csc[i]; int ii = cidx[i]; int rank = 0;
        for (int t = 0; t < ncand; ++t) {
            float st = csc[t];
            rank += (st > si || (st == si && cidx[t] < ii)) ? 1 : 0;
        }
        if (rank < CHOOSEK) { pn += cjv[i]; pd += cjj[i]; }
    }
#pragma unroll
    for (int off = 32; off > 0; off >>= 1) {
        pn += __shfl_xor(pn, off, 64);
        pd += __shfl_xor(pd, off, 64);
    }
    if (lane == 0) { wred[wave] = pn; wred[4 + wave] = pd; }
    __syncthreads();
    if (tid == 0) {
        float n = wred[0] + wred[1] + wred[2] + wred[3];
        float d = wred[4] + wred[5] + wred[6] + wred[7];
        out[b] = n / d;
    }
}

// -------------------------------------------------------------------------
extern "C" void kernel_launch(void* const* d_in, const int* in_sizes, int n_in,
                              void* d_out, int out_size, void* d_ws, size_t ws_size,
                              hipStream_t stream)
{
    (void)in_sizes; (void)n_in; (void)out_size; (void)ws_size;
    const float* q    = (const float*)d_in[0];
    const float* key  = (const float*)d_in[1];
    const float* hist = (const float*)d_in[2];
    const float* vals = (const float*)d_in[3];
    float* out = (float*)d_out;
    unsigned short* s16 = (unsigned short*)d_ws;   // 1024*65536*2 = 128 MiB

    dim3 g1(BATCH / 128, MSIZE / 128);
    score_u16_kernel<<<g1, 256, 0, stream>>>(q, key, hist, s16);
    chunk_select_kernel<<<BATCH * 4, 256, 0, stream>>>(s16);
    rescore_kernel<<<BATCH, 256, 0, stream>>>(q, key, hist, vals, s16, out);
}

// Round 5
// 601.948 us; speedup vs baseline: 2.0089x; 2.0089x over previous
//
#include <hip/hip_runtime.h>

#define BATCH   1024
#define MSIZE   65536
#define KDIM    256
#define CHOOSEK 128
#define SELK    160      // per-quarter screening depth: margin over 128 absorbs bf16+u16 reorder
#define CAP     448      // per-quarter candidate cap (ties head-room; typ ~165 used)
#define BETA    1e-8f
#define ALPHA   0.5f

typedef short bf16x8 __attribute__((ext_vector_type(8)));
typedef float f32x4  __attribute__((ext_vector_type(4)));

#define LDA 40    // bf16 LDS row: 32 + 8 pad (80 B, 16B-aligned, conflict-free spread)
#define LDC 136   // u16 epilogue tile row: 128 + 8 pad (272 B, 16B-aligned)

__device__ inline unsigned int pack2bf(float a, float b) {   // RNE fp32->bf16 pair
    unsigned int ua = __float_as_uint(a);
    unsigned int ub = __float_as_uint(b);
    ua += 0x7fffu + ((ua >> 16) & 1u);
    ub += 0x7fffu + ((ub >> 16) & 1u);
    return (ua >> 16) | (ub & 0xffff0000u);
}

// -------------------------------------------------------------------------
// K0: one-shot fp32 -> bf16 conversion of key (and q).
// -------------------------------------------------------------------------
__global__ __launch_bounds__(256)
void convert_bf16_kernel(const float* __restrict__ q,
                         const float* __restrict__ key,
                         unsigned short* __restrict__ qb,
                         unsigned short* __restrict__ kb)
{
    const int t = blockIdx.x * 256 + threadIdx.x;
    const int nk4 = (MSIZE * KDIM) / 4;    // 4,194,304
    const int nq4 = (BATCH * KDIM) / 4;    // 65,536
    if (t < nk4) {
        float4 v = ((const float4*)key)[t];
        ((uint2*)kb)[t] = make_uint2(pack2bf(v.x, v.y), pack2bf(v.z, v.w));
    } else if (t - nk4 < nq4) {
        int u = t - nk4;
        float4 v = ((const float4*)q)[u];
        ((uint2*)qb)[u] = make_uint2(pack2bf(v.x, v.y), pack2bf(v.z, v.w));
    }
}

// -------------------------------------------------------------------------
// K1 (fast path): bf16-MFMA screening GEMM from pre-converted bf16 inputs.
// 128x128 tile / 256 threads, 4 waves x (4x4 of 16x16x32 MFMA), BK=32.
// Epilogue: linear-domain monotone u16 key  sc=exp(sim-1)*(hist+beta),
// key16 = bits(sc)>>16 (sc>0), staged in LDS (aliased over As/Bs in two
// 64-row halves), written out coalesced: 4 threads/row x 64 B each.
// -------------------------------------------------------------------------
__global__ __launch_bounds__(256)
void score_fast_kernel(const unsigned short* __restrict__ qb,
                       const unsigned short* __restrict__ kb,
                       const float* __restrict__ hist,
                       unsigned short* __restrict__ s16)
{
    __shared__ __align__(16) unsigned short smem[2 * 128 * LDA];  // 20480 B
    unsigned short* As = smem;
    unsigned short* Bs = smem + 128 * LDA;
    unsigned short* Cs = smem;            // aliased after main loop (64*LDC*2=17408 B)

    const int tid  = threadIdx.x;
    const int b0   = blockIdx.x * 128;
    const int n0   = blockIdx.y * 128;
    const int lane = tid & 63;
    const int wave = tid >> 6;
    const int wm   = (wave >> 1) * 64;
    const int wn   = (wave & 1) * 64;
    const int l15  = lane & 15;
    const int l4   = lane >> 4;

    const int srow  = tid >> 1;           // 0..127
    const int shalf = tid & 1;            // 16 bf16 (32 B) halves

    f32x4 acc[4][4] = {};

    const unsigned short* gA = qb + (size_t)(b0 + srow) * KDIM + shalf * 16;
    const unsigned short* gB = kb + (size_t)(n0 + srow) * KDIM + shalf * 16;
    uint4* wAp = (uint4*)&As[srow * LDA + shalf * 16];
    uint4* wBp = (uint4*)&Bs[srow * LDA + shalf * 16];

    for (int ks = 0; ks < KDIM; ks += 32) {
        uint4 a0 = ((const uint4*)(gA + ks))[0];
        uint4 a1 = ((const uint4*)(gA + ks))[1];
        uint4 c0 = ((const uint4*)(gB + ks))[0];
        uint4 c1 = ((const uint4*)(gB + ks))[1];
        wAp[0] = a0; wAp[1] = a1;
        wBp[0] = c0; wBp[1] = c1;
        __syncthreads();

        bf16x8 af[4], bfr[4];
#pragma unroll
        for (int i = 0; i < 4; ++i)
            af[i] = *(const bf16x8*)&As[(wm + i * 16 + l15) * LDA + l4 * 8];
#pragma unroll
        for (int j = 0; j < 4; ++j)
            bfr[j] = *(const bf16x8*)&Bs[(wn + j * 16 + l15) * LDA + l4 * 8];
#pragma unroll
        for (int i = 0; i < 4; ++i)
#pragma unroll
            for (int j = 0; j < 4; ++j)
                acc[i][j] = __builtin_amdgcn_mfma_f32_16x16x32_bf16(af[i], bfr[j], acc[i][j], 0, 0, 0);
        __syncthreads();
    }

    float hj[4];
#pragma unroll
    for (int j = 0; j < 4; ++j)
        hj[j] = hist[n0 + wn + j * 16 + l15] + BETA;

    // epilogue in two 64-row halves; C/D layout: col=lane&15, row=(lane>>4)*4+reg
#pragma unroll
    for (int h = 0; h < 2; ++h) {
        if ((wave >> 1) == h) {
#pragma unroll
            for (int i = 0; i < 4; ++i) {
                int r = i * 16 + l4 * 4;
#pragma unroll
                for (int j = 0; j < 4; ++j) {
                    int c = wn + j * 16 + l15;
#pragma unroll
                    for (int reg = 0; reg < 4; ++reg) {
                        float sc = __expf(acc[i][j][reg] - 1.0f) * hj[j];
                        Cs[(r + reg) * LDC + c] = (unsigned short)(__float_as_uint(sc) >> 16);
                    }
                }
            }
        }
        __syncthreads();
        {   // full row coverage: 4 threads/row, 64 B (4 x uint4) each
            int r = tid >> 2, qq = tid & 3;
            const uint4* sp = (const uint4*)&Cs[r * LDC + qq * 32];
            uint4* dp = (uint4*)(s16 + (size_t)(b0 + h * 64 + r) * MSIZE + n0 + qq * 32);
            dp[0] = sp[0]; dp[1] = sp[1]; dp[2] = sp[2]; dp[3] = sp[3];
        }
        __syncthreads();
    }
}

// -------------------------------------------------------------------------
// K1 (fallback, small ws): fused fp32->bf16 convert + MFMA, same epilogue.
// -------------------------------------------------------------------------
__global__ __launch_bounds__(256)
void score_fused_kernel(const float* __restrict__ q,
                        const float* __restrict__ key,
                        const float* __restrict__ hist,
                        unsigned short* __restrict__ s16)
{
    __shared__ __align__(16) unsigned short smem[2 * 128 * LDA];
    unsigned short* As = smem;
    unsigned short* Bs = smem + 128 * LDA;
    unsigned short* Cs = smem;

    const int tid  = threadIdx.x;
    const int b0   = blockIdx.x * 128;
    const int n0   = blockIdx.y * 128;
    const int lane = tid & 63;
    const int wave = tid >> 6;
    const int wm   = (wave >> 1) * 64;
    const int wn   = (wave & 1) * 64;
    const int l15  = lane & 15;
    const int l4   = lane >> 4;

    const int srow = tid >> 1;
    const int sseg = (tid & 1) * 16;

    f32x4 acc[4][4] = {};

    const float* gA = q   + (size_t)(b0 + srow) * KDIM + sseg;
    const float* gB = key + (size_t)(n0 + srow) * KDIM + sseg;
    uint4* wAp = (uint4*)&As[srow * LDA + sseg];
    uint4* wBp = (uint4*)&Bs[srow * LDA + sseg];

    for (int ks = 0; ks < KDIM; ks += 32) {
        float4 a0 = *(const float4*)(gA + ks);
        float4 a1 = *(const float4*)(gA + ks + 4);
        float4 a2 = *(const float4*)(gA + ks + 8);
        float4 a3 = *(const float4*)(gA + ks + 12);
        float4 c0 = *(const float4*)(gB + ks);
        float4 c1 = *(const float4*)(gB + ks + 4);
        float4 c2 = *(const float4*)(gB + ks + 8);
        float4 c3 = *(const float4*)(gB + ks + 12);
        wAp[0] = make_uint4(pack2bf(a0.x, a0.y), pack2bf(a0.z, a0.w),
                            pack2bf(a1.x, a1.y), pack2bf(a1.z, a1.w));
        wAp[1] = make_uint4(pack2bf(a2.x, a2.y), pack2bf(a2.z, a2.w),
                            pack2bf(a3.x, a3.y), pack2bf(a3.z, a3.w));
        wBp[0] = make_uint4(pack2bf(c0.x, c0.y), pack2bf(c0.z, c0.w),
                            pack2bf(c1.x, c1.y), pack2bf(c1.z, c1.w));
        wBp[1] = make_uint4(pack2bf(c2.x, c2.y), pack2bf(c2.z, c2.w),
                            pack2bf(c3.x, c3.y), pack2bf(c3.z, c3.w));
        __syncthreads();

        bf16x8 af[4], bfr[4];
#pragma unroll
        for (int i = 0; i < 4; ++i)
            af[i] = *(const bf16x8*)&As[(wm + i * 16 + l15) * LDA + l4 * 8];
#pragma unroll
        for (int j = 0; j < 4; ++j)
            bfr[j] = *(const bf16x8*)&Bs[(wn + j * 16 + l15) * LDA + l4 * 8];
#pragma unroll
        for (int i = 0; i < 4; ++i)
#pragma unroll
            for (int j = 0; j < 4; ++j)
                acc[i][j] = __builtin_amdgcn_mfma_f32_16x16x32_bf16(af[i], bfr[j], acc[i][j], 0, 0, 0);
        __syncthreads();
    }

    float hj[4];
#pragma unroll
    for (int j = 0; j < 4; ++j)
        hj[j] = hist[n0 + wn + j * 16 + l15] + BETA;
#pragma unroll
    for (int h = 0; h < 2; ++h) {
        if ((wave >> 1) == h) {
#pragma unroll
            for (int i = 0; i < 4; ++i) {
                int r = i * 16 + l4 * 4;
#pragma unroll
                for (int j = 0; j < 4; ++j) {
                    int c = wn + j * 16 + l15;
#pragma unroll
                    for (int reg = 0; reg < 4; ++reg) {
                        float sc = __expf(acc[i][j][reg] - 1.0f) * hj[j];
                        Cs[(r + reg) * LDC + c] = (unsigned short)(__float_as_uint(sc) >> 16);
                    }
                }
            }
        }
        __syncthreads();
        {   // full row coverage: 4 threads/row, 64 B (4 x uint4) each
            int r = tid >> 2, qq = tid & 3;
            const uint4* sp = (const uint4*)&Cs[r * LDC + qq * 32];
            uint4* dp = (uint4*)(s16 + (size_t)(b0 + h * 64 + r) * MSIZE + n0 + qq * 32);
            dp[0] = sp[0]; dp[1] = sp[1]; dp[2] = sp[2]; dp[3] = sp[3];
        }
        __syncthreads();
    }
}

// -------------------------------------------------------------------------
// K2: per (row, quarter) — chunk into LDS once, two-level radix select of the
// local top-SELK threshold, collect candidates (u16 >= T16), EXACT fp32
// rescore of each candidate, store (idx, score, joint, joint*v) into the
// consumed chunk front. chunk[0] = count.
// -------------------------------------------------------------------------
__global__ __launch_bounds__(256)
void chunk_select_kernel(const float* __restrict__ q,
                         const float* __restrict__ key,
                         const float* __restrict__ hist,
                         const float* __restrict__ vals,
                         unsigned short* __restrict__ s16)
{
    const int b   = blockIdx.x >> 2;
    const int qd  = blockIdx.x & 3;
    const int tid = threadIdx.x;
    unsigned short* chunk = s16 + (size_t)b * MSIZE + qd * 16384;

    __shared__ unsigned short data[16384];       // 32 KB
    __shared__ unsigned int hcnt[16 * 257];
    __shared__ int stot[256];
    __shared__ int scal[4];                      // 0:H 1:nAbove 2:T16 3:count
    __shared__ float qs[KDIM];
    __shared__ int cidx[CAP];

    qs[tid] = q[(size_t)b * KDIM + tid];
    for (int i = tid; i < 16 * 257; i += 256) hcnt[i] = 0u;
    __syncthreads();

    uint4 v[8];
    const uint4* src = (const uint4*)chunk;
#pragma unroll
    for (int i = 0; i < 8; ++i) v[i] = src[i * 256 + tid];   // all loads in flight
    const int rep = (tid & 15) * 257;
#pragma unroll
    for (int i = 0; i < 8; ++i) {
        ((uint4*)data)[i * 256 + tid] = v[i];
        unsigned int w[4] = {v[i].x, v[i].y, v[i].z, v[i].w};
#pragma unroll
        for (int k = 0; k < 4; ++k) {
            atomicAdd(&hcnt[rep + ((w[k] >> 8) & 0xffu)], 1u);
            atomicAdd(&hcnt[rep + (w[k] >> 24)], 1u);
        }
    }
    __syncthreads();
    { unsigned int t = 0;
#pragma unroll
      for (int k = 0; k < 16; ++k) t += hcnt[k * 257 + tid];
      stot[tid] = (int)t; }
    __syncthreads();
    for (int off = 1; off < 256; off <<= 1) {
        int val = stot[tid] + ((tid + off < 256) ? stot[tid + off] : 0);
        __syncthreads(); stot[tid] = val; __syncthreads();
    }
    { int sH = stot[tid], sN = (tid < 255) ? stot[tid + 1] : 0;
      if (sH >= SELK && sN < SELK) { scal[0] = tid; scal[1] = sN; } }
    __syncthreads();
    const int H = scal[0], nAbove = scal[1];

    for (int i = tid; i < 16 * 257; i += 256) hcnt[i] = 0u;
    __syncthreads();
    for (int i = 0; i < 8; ++i) {
        uint4 w4 = ((const uint4*)data)[i * 256 + tid];
        unsigned int w[4] = {w4.x, w4.y, w4.z, w4.w};
#pragma unroll
        for (int k = 0; k < 4; ++k) {
            unsigned int u0 = w[k] & 0xffffu, u1 = w[k] >> 16;
            if ((int)(u0 >> 8) == H) atomicAdd(&hcnt[rep + (u0 & 0xffu)], 1u);
            if ((int)(u1 >> 8) == H) atomicAdd(&hcnt[rep + (u1 & 0xffu)], 1u);
        }
    }
    __syncthreads();
    { unsigned int t = 0;
#pragma unroll
      for (int k = 0; k < 16; ++k) t += hcnt[k * 257 + tid];
      stot[tid] = (int)t; }
    __syncthreads();
    for (int off = 1; off < 256; off <<= 1) {
        int val = stot[tid] + ((tid + off < 256) ? stot[tid + off] : 0);
        __syncthreads(); stot[tid] = val; __syncthreads();
    }
    { int sH2 = nAbove + stot[tid];
      int sN2 = nAbove + ((tid < 255) ? stot[tid + 1] : 0);
      if (sH2 >= SELK && sN2 < SELK) scal[2] = (H << 8) | tid;
      if (tid == 0) scal[3] = 0; }
    __syncthreads();
    const unsigned int T16 = (unsigned int)scal[2];

    for (int i = 0; i < 8; ++i) {
        uint4 w4 = ((const uint4*)data)[i * 256 + tid];
        int base = (i * 256 + tid) * 8;
        unsigned int w[4] = {w4.x, w4.y, w4.z, w4.w};
#pragma unroll
        for (int k = 0; k < 4; ++k) {
            unsigned int u0 = w[k] & 0xffffu, u1 = w[k] >> 16;
            if (u0 >= T16) { int p = atomicAdd(&scal[3], 1);
                             if (p < CAP) cidx[p] = qd * 16384 + base + 2 * k; }
            if (u1 >= T16) { int p = atomicAdd(&scal[3], 1);
                             if (p < CAP) cidx[p] = qd * 16384 + base + 2 * k + 1; }
        }
    }
    __syncthreads();
    const int n = min(scal[3], CAP);

    // exact fp32 rescore; results to chunk front
    int*   ip = (int*)(chunk + 32);              // byte 64
    float* fp = (float*)(chunk + 32 + 2 * CAP);  // byte 64 + 4*CAP
    const int wave = tid >> 6, lane = tid & 63;
    for (int i = wave; i < n; i += 4) {
        const int idx = cidx[i];
        float4 kk = *(const float4*)&key[(size_t)idx * KDIM + lane * 4];
        float4 qq = *(const float4*)&qs[lane * 4];
        float p = kk.x * qq.x + kk.y * qq.y + kk.z * qq.z + kk.w * qq.w;
#pragma unroll
        for (int off = 32; off > 0; off >>= 1) p += __shfl_xor(p, off, 64);
        if (lane == 0) {
            float e = expf(p - 1.0f);
            float h = hist[idx];
            float j = e * (ALPHA * h + BETA);
            ip[i]           = idx;
            fp[i]           = e * (h + BETA);    // selection score
            fp[CAP + i]     = j;
            fp[2 * CAP + i] = j * vals[idx];
        }
    }
    if (tid == 0) chunk[0] = (unsigned short)n;
}

// -------------------------------------------------------------------------
// K3: per row — gather precomputed (idx, csc, cjj, cjv) from 4 chunk fronts,
// count-based exact top-128 (ties -> lower index, matches lax.top_k), reduce.
// -------------------------------------------------------------------------
__global__ __launch_bounds__(256)
void finalize_kernel(const unsigned short* __restrict__ s16,
                     float* __restrict__ out)
{
    const int b   = blockIdx.x;
    const int tid = threadIdx.x;

    __shared__ int   cidx[4 * CAP];
    __shared__ float csc[4 * CAP], cjj[4 * CAP], cjv[4 * CAP];
    __shared__ int   base[5];
    __shared__ float wred[8];

    const unsigned short* row = s16 + (size_t)b * MSIZE;
    if (tid == 0) {
        int a = 0;
#pragma unroll
        for (int qd = 0; qd < 4; ++qd) { base[qd] = a; a += row[qd * 16384]; }
        base[4] = a;
    }
    __syncthreads();
#pragma unroll
    for (int qd = 0; qd < 4; ++qd) {
        const unsigned short* ch = row + qd * 16384;
        const int*   ip = (const int*)(ch + 32);
        const float* fp = (const float*)(ch + 32 + 2 * CAP);
        int bs = base[qd], cnt = base[qd + 1] - bs;
        for (int i = tid; i < cnt; i += 256) {
            cidx[bs + i] = ip[i];
            csc[bs + i]  = fp[i];
            cjj[bs + i]  = fp[CAP + i];
            cjv[bs + i]  = fp[2 * CAP + i];
        }
    }
    __syncthreads();
    const int ncand = base[4];

    float pn = 0.f, pd = 0.f;
    for (int i = tid; i < ncand; i += 256) {
        float si = csc[i]; int ii = cidx[i]; int rank = 0;
        for (int t = 0; t < ncand; ++t) {
            float st = csc[t];
            rank += (st > si || (st == si && cidx[t] < ii)) ? 1 : 0;
        }
        if (rank < CHOOSEK) { pn += cjv[i]; pd += cjj[i]; }
    }
    const int wave = tid >> 6, lane = tid & 63;
#pragma unroll
    for (int off = 32; off > 0; off >>= 1) {
        pn += __shfl_xor(pn, off, 64);
        pd += __shfl_xor(pd, off, 64);
    }
    if (lane == 0) { wred[wave] = pn; wred[4 + wave] = pd; }
    __syncthreads();
    if (tid == 0) {
        float n = wred[0] + wred[1] + wred[2] + wred[3];
        float d = wred[4] + wred[5] + wred[6] + wred[7];
        out[b] = n / d;
    }
}

// -------------------------------------------------------------------------
extern "C" void kernel_launch(void* const* d_in, const int* in_sizes, int n_in,
                              void* d_out, int out_size, void* d_ws, size_t ws_size,
                              hipStream_t stream)
{
    (void)in_sizes; (void)n_in; (void)out_size;
    const float* q    = (const float*)d_in[0];
    const float* key  = (const float*)d_in[1];
    const float* hist = (const float*)d_in[2];
    const float* vals = (const float*)d_in[3];
    float* out = (float*)d_out;

    unsigned short* s16 = (unsigned short*)d_ws;                 // 128 MiB
    unsigned short* kb  = s16 + (size_t)BATCH * MSIZE;           // 32 MiB
    unsigned short* qb  = kb + (size_t)MSIZE * KDIM;             // 0.5 MiB
    const size_t need = ((size_t)BATCH * MSIZE + (size_t)MSIZE * KDIM
                         + (size_t)BATCH * KDIM) * 2;

    dim3 g1(BATCH / 128, MSIZE / 128);
    if (ws_size >= need) {
        convert_bf16_kernel<<<(MSIZE * KDIM / 4 + BATCH * KDIM / 4) / 256, 256, 0, stream>>>(q, key, qb, kb);
        score_fast_kernel<<<g1, 256, 0, stream>>>(qb, kb, hist, s16);
    } else {
        score_fused_kernel<<<g1, 256, 0, stream>>>(q, key, hist, s16);
    }
    chunk_select_kernel<<<BATCH * 4, 256, 0, stream>>>(q, key, hist, vals, s16);
    finalize_kernel<<<BATCH, 256, 0, stream>>>(s16, out);
}

// Round 7
// 446.187 us; speedup vs baseline: 2.7102x; 1.3491x over previous
//
#include <hip/hip_runtime.h>

#define BATCH   1024
#define MSIZE   65536
#define KDIM    256
#define CHOOSEK 128
#define SELK    160      // per-quarter screening depth: margin over 128 absorbs bf16+u16 reorder
#define CAP     512      // per-quarter candidate cap (exact 16-bit threshold -> typ ~165 used)
#define BETA    1e-8f
#define ALPHA   0.5f

typedef short bf16x8 __attribute__((ext_vector_type(8)));
typedef float f32x4  __attribute__((ext_vector_type(4)));

#define LDA 72    // bf16 LDS row for BK=64: 64 + 8 pad (144 B, 16B-aligned)
#define LDAF 40   // fallback BK=32 row
#define LDC 136   // u16 epilogue tile row: 128 + 8 pad

__device__ inline unsigned int pack2bf(float a, float b) {   // RNE fp32->bf16 pair
    unsigned int ua = __float_as_uint(a);
    unsigned int ub = __float_as_uint(b);
    ua += 0x7fffu + ((ua >> 16) & 1u);
    ub += 0x7fffu + ((ub >> 16) & 1u);
    return (ua >> 16) | (ub & 0xffff0000u);
}

// -------------------------------------------------------------------------
// K0: one-shot fp32 -> bf16 conversion of key (and q).
// -------------------------------------------------------------------------
__global__ __launch_bounds__(256)
void convert_bf16_kernel(const float* __restrict__ q,
                         const float* __restrict__ key,
                         unsigned short* __restrict__ qb,
                         unsigned short* __restrict__ kb)
{
    const int t = blockIdx.x * 256 + threadIdx.x;
    const int nk4 = (MSIZE * KDIM) / 4;
    const int nq4 = (BATCH * KDIM) / 4;
    if (t < nk4) {
        float4 v = ((const float4*)key)[t];
        ((uint2*)kb)[t] = make_uint2(pack2bf(v.x, v.y), pack2bf(v.z, v.w));
    } else if (t - nk4 < nq4) {
        int u = t - nk4;
        float4 v = ((const float4*)q)[u];
        ((uint2*)qb)[u] = make_uint2(pack2bf(v.x, v.y), pack2bf(v.z, v.w));
    }
}

// -------------------------------------------------------------------------
// K1 (fast path): bf16-MFMA screening GEMM, BK=64 (4 stages). 128x128 tile /
// 256 threads, 4 waves x 4x4 of 16x16x32 MFMA. Epilogue: u16 key =
// bits(exp(sim-1)*(hist+beta))>>16, staged in LDS (aliased), coalesced out.
// -------------------------------------------------------------------------
__global__ __launch_bounds__(256)
void score_fast_kernel(const unsigned short* __restrict__ qb,
                       const unsigned short* __restrict__ kb,
                       const float* __restrict__ hist,
                       unsigned short* __restrict__ s16)
{
    __shared__ __align__(16) unsigned short smem[2 * 128 * LDA];  // 36864 B
    unsigned short* As = smem;
    unsigned short* Bs = smem + 128 * LDA;
    unsigned short* Cs = smem;            // aliased epilogue tile (64*LDC*2 = 17408 B)

    const int tid  = threadIdx.x;
    const int b0   = blockIdx.x * 128;
    const int n0   = blockIdx.y * 128;
    const int lane = tid & 63;
    const int wave = tid >> 6;
    const int wm   = (wave >> 1) * 64;
    const int wn   = (wave & 1) * 64;
    const int l15  = lane & 15;
    const int l4   = lane >> 4;

    const int srow  = tid >> 1;           // 0..127
    const int shalf = (tid & 1) * 32;     // 32-element (64 B) halves of BK=64

    f32x4 acc[4][4] = {};

    const unsigned short* gA = qb + (size_t)(b0 + srow) * KDIM + shalf;
    const unsigned short* gB = kb + (size_t)(n0 + srow) * KDIM + shalf;
    uint4* wAp = (uint4*)&As[srow * LDA + shalf];
    uint4* wBp = (uint4*)&Bs[srow * LDA + shalf];

    for (int ks = 0; ks < KDIM; ks += 64) {
        uint4 a[4], c[4];
#pragma unroll
        for (int t = 0; t < 4; ++t) a[t] = ((const uint4*)(gA + ks))[t];
#pragma unroll
        for (int t = 0; t < 4; ++t) c[t] = ((const uint4*)(gB + ks))[t];
#pragma unroll
        for (int t = 0; t < 4; ++t) { wAp[t] = a[t]; wBp[t] = c[t]; }
        __syncthreads();

#pragma unroll
        for (int s = 0; s < 2; ++s) {
            bf16x8 af[4], bfr[4];
#pragma unroll
            for (int i = 0; i < 4; ++i)
                af[i] = *(const bf16x8*)&As[(wm + i * 16 + l15) * LDA + s * 32 + l4 * 8];
#pragma unroll
            for (int j = 0; j < 4; ++j)
                bfr[j] = *(const bf16x8*)&Bs[(wn + j * 16 + l15) * LDA + s * 32 + l4 * 8];
#pragma unroll
            for (int i = 0; i < 4; ++i)
#pragma unroll
                for (int j = 0; j < 4; ++j)
                    acc[i][j] = __builtin_amdgcn_mfma_f32_16x16x32_bf16(af[i], bfr[j], acc[i][j], 0, 0, 0);
        }
        __syncthreads();
    }

    float hj[4];
#pragma unroll
    for (int j = 0; j < 4; ++j)
        hj[j] = hist[n0 + wn + j * 16 + l15] + BETA;

    // epilogue in two 64-row halves; C/D layout: col=lane&15, row=(lane>>4)*4+reg
#pragma unroll
    for (int h = 0; h < 2; ++h) {
        if ((wave >> 1) == h) {
#pragma unroll
            for (int i = 0; i < 4; ++i) {
                int r = i * 16 + l4 * 4;
#pragma unroll
                for (int j = 0; j < 4; ++j) {
                    int c = wn + j * 16 + l15;
#pragma unroll
                    for (int reg = 0; reg < 4; ++reg) {
                        float sc = __expf(acc[i][j][reg] - 1.0f) * hj[j];
                        Cs[(r + reg) * LDC + c] = (unsigned short)(__float_as_uint(sc) >> 16);
                    }
                }
            }
        }
        __syncthreads();
        {   // full row coverage: 4 threads/row, 64 B (4 x uint4) each
            int r = tid >> 2, qq = tid & 3;
            const uint4* sp = (const uint4*)&Cs[r * LDC + qq * 32];
            uint4* dp = (uint4*)(s16 + (size_t)(b0 + h * 64 + r) * MSIZE + n0 + qq * 32);
            dp[0] = sp[0]; dp[1] = sp[1]; dp[2] = sp[2]; dp[3] = sp[3];
        }
        __syncthreads();
    }
}

// -------------------------------------------------------------------------
// K1 (fallback, small ws): fused fp32->bf16 convert + MFMA, BK=32 (proven).
// -------------------------------------------------------------------------
__global__ __launch_bounds__(256)
void score_fused_kernel(const float* __restrict__ q,
                        const float* __restrict__ key,
                        const float* __restrict__ hist,
                        unsigned short* __restrict__ s16)
{
    __shared__ __align__(16) unsigned short smem[2 * 128 * LDAF];
    unsigned short* As = smem;
    unsigned short* Bs = smem + 128 * LDAF;
    unsigned short* Cs = smem;

    const int tid  = threadIdx.x;
    const int b0   = blockIdx.x * 128;
    const int n0   = blockIdx.y * 128;
    const int lane = tid & 63;
    const int wave = tid >> 6;
    const int wm   = (wave >> 1) * 64;
    const int wn   = (wave & 1) * 64;
    const int l15  = lane & 15;
    const int l4   = lane >> 4;

    const int srow = tid >> 1;
    const int sseg = (tid & 1) * 16;

    f32x4 acc[4][4] = {};

    const float* gA = q   + (size_t)(b0 + srow) * KDIM + sseg;
    const float* gB = key + (size_t)(n0 + srow) * KDIM + sseg;
    uint4* wAp = (uint4*)&As[srow * LDAF + sseg];
    uint4* wBp = (uint4*)&Bs[srow * LDAF + sseg];

    for (int ks = 0; ks < KDIM; ks += 32) {
        float4 a0 = *(const float4*)(gA + ks);
        float4 a1 = *(const float4*)(gA + ks + 4);
        float4 a2 = *(const float4*)(gA + ks + 8);
        float4 a3 = *(const float4*)(gA + ks + 12);
        float4 c0 = *(const float4*)(gB + ks);
        float4 c1 = *(const float4*)(gB + ks + 4);
        float4 c2 = *(const float4*)(gB + ks + 8);
        float4 c3 = *(const float4*)(gB + ks + 12);
        wAp[0] = make_uint4(pack2bf(a0.x, a0.y), pack2bf(a0.z, a0.w),
                            pack2bf(a1.x, a1.y), pack2bf(a1.z, a1.w));
        wAp[1] = make_uint4(pack2bf(a2.x, a2.y), pack2bf(a2.z, a2.w),
                            pack2bf(a3.x, a3.y), pack2bf(a3.z, a3.w));
        wBp[0] = make_uint4(pack2bf(c0.x, c0.y), pack2bf(c0.z, c0.w),
                            pack2bf(c1.x, c1.y), pack2bf(c1.z, c1.w));
        wBp[1] = make_uint4(pack2bf(c2.x, c2.y), pack2bf(c2.z, c2.w),
                            pack2bf(c3.x, c3.y), pack2bf(c3.z, c3.w));
        __syncthreads();

        bf16x8 af[4], bfr[4];
#pragma unroll
        for (int i = 0; i < 4; ++i)
            af[i] = *(const bf16x8*)&As[(wm + i * 16 + l15) * LDAF + l4 * 8];
#pragma unroll
        for (int j = 0; j < 4; ++j)
            bfr[j] = *(const bf16x8*)&Bs[(wn + j * 16 + l15) * LDAF + l4 * 8];
#pragma unroll
        for (int i = 0; i < 4; ++i)
#pragma unroll
            for (int j = 0; j < 4; ++j)
                acc[i][j] = __builtin_amdgcn_mfma_f32_16x16x32_bf16(af[i], bfr[j], acc[i][j], 0, 0, 0);
        __syncthreads();
    }

    float hj[4];
#pragma unroll
    for (int j = 0; j < 4; ++j)
        hj[j] = hist[n0 + wn + j * 16 + l15] + BETA;
#pragma unroll
    for (int h = 0; h < 2; ++h) {
        if ((wave >> 1) == h) {
#pragma unroll
            for (int i = 0; i < 4; ++i) {
                int r = i * 16 + l4 * 4;
#pragma unroll
                for (int j = 0; j < 4; ++j) {
                    int c = wn + j * 16 + l15;
#pragma unroll
                    for (int reg = 0; reg < 4; ++reg) {
                        float sc = __expf(acc[i][j][reg] - 1.0f) * hj[j];
                        Cs[(r + reg) * LDC + c] = (unsigned short)(__float_as_uint(sc) >> 16);
                    }
                }
            }
        }
        __syncthreads();
        {
            int r = tid >> 2, qq = tid & 3;
            const uint4* sp = (const uint4*)&Cs[r * LDC + qq * 32];
            uint4* dp = (uint4*)(s16 + (size_t)(b0 + h * 64 + r) * MSIZE + n0 + qq * 32);
            dp[0] = sp[0]; dp[1] = sp[1]; dp[2] = sp[2]; dp[3] = sp[3];
        }
        __syncthreads();
    }
}

// -------------------------------------------------------------------------
// K2: per (row, quarter) — chunk held in REGISTERS (8 x uint4/thread),
// EXACT two-level (high-byte, then low-byte) radix select of the local
// top-SELK threshold T16, collect candidates (u16 >= T16), exact fp32
// rescore (16 lanes/candidate), results to the consumed chunk front.
// chunk[0] = count.
// -------------------------------------------------------------------------
__global__ __launch_bounds__(256)
void chunk_select_kernel(const float* __restrict__ q,
                         const float* __restrict__ key,
                         const float* __restrict__ hist,
                         const float* __restrict__ vals,
                         unsigned short* __restrict__ s16)
{
    const int b   = blockIdx.x >> 2;
    const int qd  = blockIdx.x & 3;
    const int tid = threadIdx.x;
    unsigned short* chunk = s16 + (size_t)b * MSIZE + qd * 16384;

    __shared__ unsigned int hcnt[16 * 257];      // 16 replicated histograms, 16448 B
    __shared__ int   stot[256];
    __shared__ float qs[KDIM];
    __shared__ int   scal[4];                    // 0:H 1:nAbove 2:T16 3:count
    __shared__ int   cidx[CAP];

    qs[tid] = q[(size_t)b * KDIM + tid];
    for (int i = tid; i < 16 * 257; i += 256) hcnt[i] = 0u;

    uint4 v[8];
    const uint4* src = (const uint4*)chunk;
#pragma unroll
    for (int i = 0; i < 8; ++i) v[i] = src[i * 256 + tid];   // all loads in flight
    __syncthreads();

    const int rep = (tid & 15) * 257;
    // ---- pass 1: high-byte histogram (from registers) ----
#pragma unroll
    for (int i = 0; i < 8; ++i) {
        unsigned int w[4] = {v[i].x, v[i].y, v[i].z, v[i].w};
#pragma unroll
        for (int k = 0; k < 4; ++k) {
            atomicAdd(&hcnt[rep + ((w[k] >> 8) & 0xffu)], 1u);
            atomicAdd(&hcnt[rep + (w[k] >> 24)], 1u);
        }
    }
    __syncthreads();
    { unsigned int t = 0;
#pragma unroll
      for (int k = 0; k < 16; ++k) t += hcnt[k * 257 + tid];
      stot[tid] = (int)t; }
    __syncthreads();
    for (int off = 1; off < 256; off <<= 1) {    // suffix sum over high byte
        int val = stot[tid] + ((tid + off < 256) ? stot[tid + off] : 0);
        __syncthreads(); stot[tid] = val; __syncthreads();
    }
    { int sH = stot[tid], sN = (tid < 255) ? stot[tid + 1] : 0;
      if (sH >= SELK && sN < SELK) { scal[0] = tid; scal[1] = sN; } }
    __syncthreads();
    const int H = scal[0], nAbove = scal[1];

    for (int i = tid; i < 16 * 257; i += 256) hcnt[i] = 0u;
    __syncthreads();
    // ---- pass 2: low-byte histogram among entries with high byte == H ----
#pragma unroll
    for (int i = 0; i < 8; ++i) {
        unsigned int w[4] = {v[i].x, v[i].y, v[i].z, v[i].w};
#pragma unroll
        for (int k = 0; k < 4; ++k) {
            unsigned int u0 = w[k] & 0xffffu, u1 = w[k] >> 16;
            if ((int)(u0 >> 8) == H) atomicAdd(&hcnt[rep + (u0 & 0xffu)], 1u);
            if ((int)(u1 >> 8) == H) atomicAdd(&hcnt[rep + (u1 & 0xffu)], 1u);
        }
    }
    __syncthreads();
    { unsigned int t = 0;
#pragma unroll
      for (int k = 0; k < 16; ++k) t += hcnt[k * 257 + tid];
      stot[tid] = (int)t; }
    __syncthreads();
    for (int off = 1; off < 256; off <<= 1) {
        int val = stot[tid] + ((tid + off < 256) ? stot[tid + off] : 0);
        __syncthreads(); stot[tid] = val; __syncthreads();
    }
    { int sH2 = nAbove + stot[tid];
      int sN2 = nAbove + ((tid < 255) ? stot[tid + 1] : 0);
      if (sH2 >= SELK && sN2 < SELK) scal[2] = (H << 8) | tid;
      if (tid == 0) scal[3] = 0; }
    __syncthreads();
    const unsigned int T16 = (unsigned int)scal[2];

    // ---- collect candidates (u16 >= T16) from registers ----
#pragma unroll
    for (int i = 0; i < 8; ++i) {
        int base = (i * 256 + tid) * 8;
        unsigned int w[4] = {v[i].x, v[i].y, v[i].z, v[i].w};
#pragma unroll
        for (int k = 0; k < 4; ++k) {
            unsigned int u0 = w[k] & 0xffffu, u1 = w[k] >> 16;
            if (u0 >= T16) { int p = atomicAdd(&scal[3], 1);
                             if (p < CAP) cidx[p] = qd * 16384 + base + 2 * k; }
            if (u1 >= T16) { int p = atomicAdd(&scal[3], 1);
                             if (p < CAP) cidx[p] = qd * 16384 + base + 2 * k + 1; }
        }
    }
    __syncthreads();
    const int n = min(scal[3], CAP);

    // ---- exact fp32 rescore: 16 lanes per candidate ----
    int*   ip = (int*)(chunk + 32);              // byte 64
    float* fp = (float*)(chunk + 32 + 2 * CAP);  // byte 64 + 4*CAP
    const int grp = tid >> 4, sub = tid & 15;
    const float4* qs4 = (const float4*)qs;
    for (int i = grp; i < n; i += 16) {
        const int idx = cidx[i];
        const float4* kp = (const float4*)&key[(size_t)idx * KDIM];
        float p = 0.f;
#pragma unroll
        for (int j = 0; j < 4; ++j) {
            float4 kk = kp[sub + 16 * j];
            float4 qq = qs4[sub + 16 * j];
            p += kk.x * qq.x + kk.y * qq.y + kk.z * qq.z + kk.w * qq.w;
        }
        p += __shfl_xor(p, 1, 64); p += __shfl_xor(p, 2, 64);
        p += __shfl_xor(p, 4, 64); p += __shfl_xor(p, 8, 64);
        if (sub == 0) {
            float e = expf(p - 1.0f);
            float h = hist[idx];
            float jn = e * (ALPHA * h + BETA);
            ip[i]           = idx;
            fp[i]           = e * (h + BETA);    // selection score
            fp[CAP + i]     = jn;
            fp[2 * CAP + i] = jn * vals[idx];
        }
    }
    if (tid == 0) chunk[0] = (unsigned short)n;
}

// -------------------------------------------------------------------------
// K3: per row — gather precomputed (idx, csc, cjj, cjv) from 4 chunk fronts,
// count-based exact top-128 (ties -> lower index, matches lax.top_k), reduce.
// -------------------------------------------------------------------------
__global__ __launch_bounds__(256)
void finalize_kernel(const unsigned short* __restrict__ s16,
                     float* __restrict__ out)
{
    const int b   = blockIdx.x;
    const int tid = threadIdx.x;

    __shared__ int   cidx[4 * CAP];
    __shared__ float csc[4 * CAP], cjj[4 * CAP], cjv[4 * CAP];
    __shared__ int   base[5];
    __shared__ float wred[8];

    const unsigned short* row = s16 + (size_t)b * MSIZE;
    if (tid == 0) {
        int a = 0;
#pragma unroll
        for (int qd = 0; qd < 4; ++qd) { base[qd] = a; a += row[qd * 16384]; }
        base[4] = a;
    }
    __syncthreads();
#pragma unroll
    for (int qd = 0; qd < 4; ++qd) {
        const unsigned short* ch = row + qd * 16384;
        const int*   ip = (const int*)(ch + 32);
        const float* fp = (const float*)(ch + 32 + 2 * CAP);
        int bs = base[qd], cnt = base[qd + 1] - bs;
        for (int i = tid; i < cnt; i += 256) {
            cidx[bs + i] = ip[i];
            csc[bs + i]  = fp[i];
            cjj[bs + i]  = fp[CAP + i];
            cjv[bs + i]  = fp[2 * CAP + i];
        }
    }
    __syncthreads();
    const int ncand = base[4];

    float pn = 0.f, pd = 0.f;
    for (int i = tid; i < ncand; i += 256) {
        float si = csc[i]; int ii = cidx[i]; int rank = 0;
        for (int t = 0; t < ncand; ++t) {
            float st = csc[t];
            rank += (st > si || (st == si && cidx[t] < ii)) ? 1 : 0;
        }
        if (rank < CHOOSEK) { pn += cjv[i]; pd += cjj[i]; }
    }
    const int wave = tid >> 6, lane = tid & 63;
#pragma unroll
    for (int off = 32; off > 0; off >>= 1) {
        pn += __shfl_xor(pn, off, 64);
        pd += __shfl_xor(pd, off, 64);
    }
    if (lane == 0) { wred[wave] = pn; wred[4 + wave] = pd; }
    __syncthreads();
    if (tid == 0) {
        float n = wred[0] + wred[1] + wred[2] + wred[3];
        float d = wred[4] + wred[5] + wred[6] + wred[7];
        out[b] = n / d;
    }
}

// -------------------------------------------------------------------------
extern "C" void kernel_launch(void* const* d_in, const int* in_sizes, int n_in,
                              void* d_out, int out_size, void* d_ws, size_t ws_size,
                              hipStream_t stream)
{
    (void)in_sizes; (void)n_in; (void)out_size;
    const float* q    = (const float*)d_in[0];
    const float* key  = (const float*)d_in[1];
    const float* hist = (const float*)d_in[2];
    const float* vals = (const float*)d_in[3];
    float* out = (float*)d_out;

    unsigned short* s16 = (unsigned short*)d_ws;                 // 128 MiB
    unsigned short* kb  = s16 + (size_t)BATCH * MSIZE;           // 32 MiB
    unsigned short* qb  = kb + (size_t)MSIZE * KDIM;             // 0.5 MiB
    const size_t need = ((size_t)BATCH * MSIZE + (size_t)MSIZE * KDIM
                         + (size_t)BATCH * KDIM) * 2;

    dim3 g1(BATCH / 128, MSIZE / 128);
    if (ws_size >= need) {
        convert_bf16_kernel<<<(MSIZE * KDIM / 4 + BATCH * KDIM / 4) / 256, 256, 0, stream>>>(q, key, qb, kb);
        score_fast_kernel<<<g1, 256, 0, stream>>>(qb, kb, hist, s16);
    } else {
        score_fused_kernel<<<g1, 256, 0, stream>>>(q, key, hist, s16);
    }
    chunk_select_kernel<<<BATCH * 4, 256, 0, stream>>>(q, key, hist, vals, s16);
    finalize_kernel<<<BATCH, 256, 0, stream>>>(s16, out);
}